// Round 1
// baseline (23438.588 us; speedup 1.0000x reference)
//
#include <hip/hip_runtime.h>
#include <cstddef>

#define NL 10000
#define DD 100

// Transpose each layer's W[l] from [o][k] (torch out x in) to [k][o] so that
// the main kernel's per-lane output-pair loads are coalesced (row k = 400 B).
__global__ void transpose_out(const float* __restrict__ W, float* __restrict__ Wt) {
    __shared__ float tile[DD * DD];
    const size_t base = (size_t)blockIdx.x * (DD * DD);
    const float* src = W + base;
    float* dst = Wt + base;
    for (int i = threadIdx.x; i < DD * DD; i += blockDim.x) tile[i] = src[i];
    __syncthreads();
    for (int i = threadIdx.x; i < DD * DD; i += blockDim.x) {
        int o = i / DD, k = i - o * DD;          // i = o*DD + k
        dst[i] = tile[k * DD + o];                // new [o][k] slot gets W[k][o] => dst[k'][o'] = W[o'][k']
    }
}

__global__ void transpose_inplace(float* __restrict__ W) {
    __shared__ float tile[DD * DD];
    float* M = W + (size_t)blockIdx.x * (DD * DD);
    for (int i = threadIdx.x; i < DD * DD; i += blockDim.x) tile[i] = M[i];
    __syncthreads();
    for (int i = threadIdx.x; i < DD * DD; i += blockDim.x) {
        int o = i / DD, k = i - o * DD;
        M[i] = tile[k * DD + o];
    }
}

// One wave per batch row. h[100] wave-uniform in VGPRs; lane p<50 owns output
// pair (2p, 2p+1). Rolling register prefetch: wreg holds layer l's weights,
// refilled with layer l+1's pair right after each use (one-layer latency cover).
__global__ __launch_bounds__(64, 1) void hugenet_chain(
    const float* __restrict__ x,   // [256][100]
    const float* __restrict__ Wt,  // [10000][k=100][o=100] transposed
    const float* __restrict__ b,   // [10000][100]
    const float* __restrict__ Wo,  // [10][100]
    const float* __restrict__ bo,  // [10]
    float* __restrict__ out)       // [256][10]
{
    const int r = blockIdx.x;
    const int lane = threadIdx.x;
    const int p = lane < 50 ? lane : 49;          // clamp; lanes 50-63 duplicate pair 49
    const bool active = lane < 50;
    __shared__ float hbuf[DD];

    // init h = x[r][:]
    {
        float2 xv = ((const float2*)(x + (size_t)r * DD))[p];
        if (active) ((float2*)hbuf)[p] = xv;
    }
    __syncthreads();
    float h[DD];
    #pragma unroll
    for (int i = 0; i < 25; ++i) {
        float4 t = ((const float4*)hbuf)[i];
        h[4 * i + 0] = t.x; h[4 * i + 1] = t.y; h[4 * i + 2] = t.z; h[4 * i + 3] = t.w;
    }

    // prologue: load layer 0 weights into registers (wreg[k] = Wt[0][k][2p..2p+1])
    float2 wreg[DD];
    #pragma unroll
    for (int k = 0; k < DD; ++k)
        wreg[k] = *((const float2*)(Wt + (size_t)k * DD) + p);

    for (int l = 0; l < NL; ++l) {
        const int lnxt = (l + 1 < NL) ? (l + 1) : 0;   // wrap to avoid OOB prefetch
        const float2* wnext = (const float2*)(Wt + (size_t)lnxt * (DD * DD)) + p;
        float2 bias = *((const float2*)(b + (size_t)l * DD) + p);

        float a0x = 0.f, a0y = 0.f, a1x = 0.f, a1y = 0.f;  // 4 chains: even/odd k x 2 outs
        #pragma unroll
        for (int kk = 0; kk < 50; ++kk) {
            float2 w0 = wreg[2 * kk];
            float2 w1 = wreg[2 * kk + 1];
            wreg[2 * kk]     = wnext[(2 * kk) * 50];       // prefetch next layer, same pair
            wreg[2 * kk + 1] = wnext[(2 * kk + 1) * 50];
            a0x = fmaf(w0.x, h[2 * kk], a0x);
            a0y = fmaf(w0.y, h[2 * kk], a0y);
            a1x = fmaf(w1.x, h[2 * kk + 1], a1x);
            a1y = fmaf(w1.y, h[2 * kk + 1], a1y);
        }
        float yx = fmaxf(a0x + a1x + bias.x, 0.f);
        float yy = fmaxf(a0y + a1y + bias.y, 0.f);

        __syncthreads();
        if (active) ((float2*)hbuf)[p] = make_float2(yx, yy);
        __syncthreads();
        #pragma unroll
        for (int i = 0; i < 25; ++i) {
            float4 t = ((const float4*)hbuf)[i];
            h[4 * i + 0] = t.x; h[4 * i + 1] = t.y; h[4 * i + 2] = t.z; h[4 * i + 3] = t.w;
        }
    }

    // final Linear(100 -> 10), no relu
    if (lane < 10) {
        float acc = bo[lane];
        #pragma unroll 4
        for (int k = 0; k < DD; ++k)
            acc = fmaf(Wo[lane * DD + k], h[k], acc);
        out[(size_t)r * 10 + lane] = acc;
    }
}

extern "C" void kernel_launch(void* const* d_in, const int* in_sizes, int n_in,
                              void* d_out, int out_size, void* d_ws, size_t ws_size,
                              hipStream_t stream) {
    const float* x  = (const float*)d_in[0];
    float*       W  = (float*)d_in[1];
    const float* b  = (const float*)d_in[2];
    const float* Wo = (const float*)d_in[3];
    const float* bo = (const float*)d_in[4];
    float* out = (float*)d_out;

    const size_t wbytes = (size_t)NL * DD * DD * sizeof(float);  // 400 MB
    const float* Wt;
    if (ws_size >= wbytes) {
        float* wt = (float*)d_ws;
        hipLaunchKernelGGL(transpose_out, dim3(NL), dim3(256), 0, stream, W, wt);
        Wt = wt;
    } else {
        // in place: harness restores d_in from pristine copy before every launch
        hipLaunchKernelGGL(transpose_inplace, dim3(NL), dim3(256), 0, stream, W);
        Wt = W;
    }
    hipLaunchKernelGGL(hugenet_chain, dim3(256), dim3(64), 0, stream, x, Wt, b, Wo, bo, out);
}